// Round 10
// baseline (223.387 us; speedup 1.0000x reference)
//
#include <hip/hip_runtime.h>
#include <hip/hip_bf16.h>

typedef __hip_bfloat16 bf16;
typedef __attribute__((ext_vector_type(8))) short bf16x8;
typedef __attribute__((ext_vector_type(4))) float f32x4;

#define NNODE 512
#define NEDGE 16384
#define INLEN 17929
#define K1    1056

// ---- workspace layout (offsets in floats) ----
#define WS_MMP     0         // 128 (64 min partials, 64 max)
#define WS_STOPV   128       // 512
#define WS_AE      640       // 16
#define WS_PS      656       // 4096
#define WS_H       5120      // 512*256
#define WS_G2WT    136192    // 256*256
#define WS_H2      201728    // 512*256
#define WS_ASRC    332800    // 512*8
#define WS_ADST    336896    // 512*8
#define WS_UV      340992    // 512*64
#define WS_K       373760    // 512
#define WS_APACK   374272    // bf16 512*1056 -> 270336 floats
#define WS_BPACK   644608    // bf16 512*1056 -> 270336 floats
#define WS_OUT1    914944    // bf16 512*512  -> 131072 floats
#define WS_WC2B    1046016   // bf16 512*512  -> 131072 floats
#define WS_WESF    1177088   // 64*256
#define WS_ASRC2   1193472   // 512*8
#define WS_ADST2   1197568   // 512*8
// end = 1201664 floats ≈ 4.8 MB

// ============ K1: fused prep (all input-only, fully parallel) ===============
// b<512: layer-1 h + logits | b==512: stopv + AE dots | b 513-514: wes pack
// b 515-578: minmax partials | b 579-594: PS/PD | b 595-610: g2W transpose
__global__ __launch_bounds__(256)
void k_prep(const float* __restrict__ demand, const float* __restrict__ W1,
            const float* __restrict__ att_s, const float* __restrict__ att_d,
            const int* __restrict__ stops, const float* __restrict__ Wes,
            const float* __restrict__ dist,
            const float* __restrict__ g1We, const float* __restrict__ g1ae,
            const float* __restrict__ g2We, const float* __restrict__ g2ae,
            const float* __restrict__ g2W,  const float* __restrict__ g2as,
            const float* __restrict__ g2ad, float* ws){
  int b = blockIdx.x, tid = threadIdx.x;
  if (b < 512){
    int hd = tid>>5, c = tid&31;
    float hv = demand[b] * W1[tid];
    ws[WS_H + b*256 + tid] = hv;
    float ps = hv * att_s[tid];
    float pd = hv * att_d[tid];
    for (int off=16; off; off>>=1){ ps += __shfl_down(ps,off,32); pd += __shfl_down(pd,off,32); }
    if (c==0){ ws[WS_ASRC + b*8+hd]=ps; ws[WS_ADST + b*8+hd]=pd; }
  } else if (b == 512){
    ws[WS_STOPV+tid] = 0.f; ws[WS_STOPV+256+tid] = 0.f;
    __syncthreads();
    ws[WS_STOPV + stops[tid]] = 1.0f;
    if (tid < 8){
      float s=0.f; for (int c=0;c<32;c++) s += g1We[tid*32+c]*g1ae[tid*32+c];
      ws[WS_AE+tid]=s;
    } else if (tid < 16){
      int h=tid-8; float s=0.f; for (int c=0;c<32;c++) s += g2We[h*32+c]*g2ae[h*32+c];
      ws[WS_AE+8+h]=s;
    }
  } else if (b < 515){
    for (int idx = (b-513)*8192 + tid; idx < (b-512)*8192; idx += 256){
      int k = idx>>8, c = idx&255;
      ws[WS_WESF+idx] = (k<32) ? Wes[k*512+c] : Wes[(k-32)*512+256+c];
    }
  } else if (b < 579){
    __shared__ float smn[256], smx[256];
    int p = b-515;
    float mn = 3.4e38f, mx = -3.4e38f;
    for (int k=0;k<16;k++){
      float v = dist[p*4096 + k*256 + tid];
      mn = fminf(mn,v); mx = fmaxf(mx,v);
    }
    smn[tid]=mn; smx[tid]=mx; __syncthreads();
    for (int off=128; off; off>>=1){
      if (tid<off){ smn[tid]=fminf(smn[tid],smn[tid+off]); smx[tid]=fmaxf(smx[tid],smx[tid+off]); }
      __syncthreads();
    }
    if (tid==0){ ws[WS_MMP+p]=smn[0]; ws[WS_MMP+64+p]=smx[0]; }
  } else if (b < 595){
    int j = b-579;
    const float* att = (j<8) ? g2as : g2ad;
    int h = j&7;
    float s = 0.f;
    for (int c=0;c<32;c++) s += att[h*32+c] * g2W[(h*32+c)*256 + tid];
    ws[WS_PS + j*256 + tid] = s;
  } else {
    __shared__ float T[64][65];
    int tb = b-595, tr = tb>>2, tc = tb&3;
    int w = tid>>6, c = tid&63;
    for (int k=0;k<16;k++){
      int r = k*4 + w;
      T[r][c] = g2W[(tr*64+r)*256 + tc*64 + c];
    }
    __syncthreads();
    for (int k=0;k<16;k++){
      int r = k*4 + w;
      ws[WS_G2WT + (tc*64+r)*256 + tr*64 + c] = T[c][r];
    }
  }
}

// ============ GAT aggregate, self-gathering edges (no CSR) ==================
// MODE 1: +h2+logits2 epilogue | MODE 2: +uv+packA epilogue
template<int MODE>
__global__ __launch_bounds__(256)
void k_agg(const float* __restrict__ hbuf, const float* __restrict__ asrc,
           const float* __restrict__ adst, const int* __restrict__ eidx,
           const float* __restrict__ markov, const float* __restrict__ AEp,
           const float* __restrict__ bvec, const float* __restrict__ dist,
           float* ws){
  int t = blockIdx.x, tid = threadIdx.x, hd = tid>>5;
  __shared__ int   srcE[256];
  __shared__ float eaE[256];
  __shared__ float Lall[256*8];
  __shared__ float AE[8], mh[8], dh[8], sw[8];
  __shared__ float xrow[256], uvrow[64];
  __shared__ int   cnt;
  __shared__ float easum;
  __shared__ float mnS, mxS;
  if (tid==0){ cnt=0; easum=0.f; }
  if (tid<8) AE[tid]=AEp[tid];
  __syncthreads();
  // ---- find this target's edges (eidx resident in L2) ----
  for (int e0=0; e0<NEDGE; e0+=256){
    int col = eidx[NEDGE+e0+tid];
    if (col==t){
      int p = atomicAdd(&cnt,1);
      int row = eidx[e0+tid];
      float a = markov[row*NNODE+t];
      if (p<256){ srcE[p]=row; eaE[p]=a; }
      atomicAdd(&easum, a);
    }
  }
  __syncthreads();
  int d = cnt<256 ? cnt : 256;
  float lattr = easum / (float)(cnt>1 ? cnt : 1);
  // ---- all edge logits -> LDS ----
  {
    int h8 = tid&7, eq = tid>>3;
    float adt = adst[t*8+h8], aeh = AE[h8];
    for (int e = eq; e < d; e += 32){
      int s = srcE[e];
      float a = asrc[s*8+h8] + adt + eaE[e]*aeh;
      Lall[e*8+h8] = a>=0.f ? a : 0.2f*a;
    }
  }
  __syncthreads();
  // ---- per-head max / denom (32 lanes per head) ----
  {
    int h = tid>>5, j = tid&31;
    float aself = asrc[t*8+h] + adst[t*8+h] + lattr*AE[h];
    aself = aself>=0.f ? aself : 0.2f*aself;
    float mm = aself;
    for (int e=j; e<d; e+=32) mm = fmaxf(mm, Lall[e*8+h]);
    for (int off=16; off; off>>=1) mm = fmaxf(mm, __shfl_down(mm,off,32));
    mm = __shfl(mm, 0, 32);
    float dd = 0.f;
    for (int e=j; e<d; e+=32) dd += __expf(Lall[e*8+h]-mm);
    for (int off=16; off; off>>=1) dd += __shfl_down(dd,off,32);
    if (j==0){
      float se = __expf(aself-mm);
      mh[h]=mm; dh[h]=dd+se+1e-16f; sw[h]=se;
    }
  }
  __syncthreads();
  // ---- logits -> unnormalized weights ----
  {
    int h8 = tid&7;
    for (int e = tid>>3; e < d; e += 32)
      Lall[e*8+h8] = __expf(Lall[e*8+h8] - mh[h8]);
  }
  __syncthreads();
  // ---- gather-accumulate (4-way ILP) ----
  float a0 = sw[hd]*hbuf[t*256+tid], a1=0.f, a2=0.f, a3=0.f;
  int e = 0;
  for (; e+4<=d; e+=4){
    a0 += Lall[(e+0)*8+hd]*hbuf[srcE[e+0]*256+tid];
    a1 += Lall[(e+1)*8+hd]*hbuf[srcE[e+1]*256+tid];
    a2 += Lall[(e+2)*8+hd]*hbuf[srcE[e+2]*256+tid];
    a3 += Lall[(e+3)*8+hd]*hbuf[srcE[e+3]*256+tid];
  }
  for (; e<d; e++) a0 += Lall[e*8+hd]*hbuf[srcE[e]*256+tid];
  float v = fmaxf(((a0+a1)+(a2+a3))/dh[hd] + bvec[tid], 0.f);
  xrow[tid] = v;
  __syncthreads();
  if (MODE == 1){
    // h2 row: xrow @ g2W^T via pre-transposed g2WT (coalesced, 4-acc ILP)
    const float* g2wt = ws + WS_G2WT;
    float h0=0.f,h1=0.f,h2=0.f,h3=0.f;
    for (int c=0;c<256;c+=4){
      h0 += xrow[c+0]*g2wt[(c+0)*256+tid];
      h1 += xrow[c+1]*g2wt[(c+1)*256+tid];
      h2 += xrow[c+2]*g2wt[(c+2)*256+tid];
      h3 += xrow[c+3]*g2wt[(c+3)*256+tid];
    }
    ws[WS_H2 + t*256 + tid] = (h0+h1)+(h2+h3);
    // layer-2 logits via PS
    if (tid < 64){
      int j = tid>>2, q = tid&3;
      const float* pr = ws + WS_PS + j*256 + q*64;
      const float* xr = xrow + q*64;
      float p = 0.f;
      for (int c=0;c<64;c++) p += xr[c]*pr[c];
      p += __shfl_down(p,2,4);
      p += __shfl_down(p,1,4);
      if (q==0){
        if (j<8) ws[WS_ASRC2 + t*8+j] = p;
        else     ws[WS_ADST2 + t*8+(j-8)] = p;
      }
    }
  } else {
    // uv row
    int k = tid>>2, q = tid&3;
    const float* wr = ws + WS_WESF + k*256 + q*64;
    const float* xr = xrow + q*64;
    float p = 0.f;
    for (int c=0;c<64;c++) p += xr[c]*wr[c];
    p += __shfl_down(p,2,4);
    p += __shfl_down(p,1,4);
    if (q==0){ ws[WS_UV + t*64+k] = p; uvrow[k] = p; }
    // dist min/max from partials (64-lane shuffle reduce)
    if (tid < 64){
      float mn = ws[WS_MMP+tid], mx = ws[WS_MMP+64+tid];
      for (int off=32; off; off>>=1){
        mn = fminf(mn, __shfl_down(mn,off));
        mx = fmaxf(mx, __shfl_down(mx,off));
      }
      if (tid==0){ mnS=mn; mxS=mx; }
    }
    __syncthreads();
    float mn = mnS, inv = 1.0f/(mxS-mnS);
    bf16* ap = (bf16*)(ws+WS_APACK);
    const float* mrow = markov + t*512;
    for (int j=tid; j<K1; j+=256){
      float v2;
      if (j<32)       v2 = uvrow[j];
      else if (j<544) v2 = (dist[t*512 + j-32] - mn) * inv;
      else            v2 = mrow[j-544];
      ap[(size_t)t*K1 + j] = __float2bfloat16(v2);
    }
  }
}

// ============ K4: sk+packB + Wc2->bf16 — 1024 thr, 4-way ILP ================
__global__ __launch_bounds__(1024)
void k_skpack(const float* __restrict__ Wc1, const float* __restrict__ bc1,
              const float* __restrict__ bes, const float* __restrict__ Wweek,
              const float* __restrict__ Wcap, const float* __restrict__ Wveh,
              const int* __restrict__ wd, const int* __restrict__ vh,
              const int* __restrict__ cp, const float* __restrict__ Wc2,
              float* ws){
  int o = blockIdx.x, tid = threadIdx.x;
  __shared__ float besf[32];
  __shared__ float red[1024];
  if (tid<32) besf[tid] = bes[tid];
  __syncthreads();
  const float* wr = Wc1 + (size_t)o*INLEN;
  bf16* bp  = (bf16*)(ws+WS_BPACK);
  bf16* w2b = (bf16*)(ws+WS_WC2B);
  float be = besf[tid&31];
  const float* uvp = ws + WS_UV + ((tid>>5)<<6) + 32 + (tid&31);
  float sP = 0.f, tP0=0.f, tP1=0.f, tP2=0.f, tP3=0.f;
  #pragma unroll
  for (int i=0;i<16;i+=4){
    float w0 = wr[tid + 1024*(i+0)];
    float w1 = wr[tid + 1024*(i+1)];
    float w2 = wr[tid + 1024*(i+2)];
    float w3 = wr[tid + 1024*(i+3)];
    float u0 = uvp[2048*(i+0)];
    float u1 = uvp[2048*(i+1)];
    float u2 = uvp[2048*(i+2)];
    float u3 = uvp[2048*(i+3)];
    sP += (w0+w1)+(w2+w3);
    tP0 += w0*(u0+be);
    tP1 += w1*(u1+be);
    tP2 += w2*(u2+be);
    tP3 += w3*(u3+be);
  }
  float tP = (tP0+tP1)+(tP2+tP3);
  if (tid < 512) tP += ws[WS_STOPV+tid] * wr[17417+tid];
  if (tid < 9){
    int g = tid/3, f = tid-g*3;
    float sv = (g==0) ? Wweek[wd[0]*3+f]
             : (g==1) ? Wcap[cp[0]*3+f]
                      : Wveh[vh[0]*3+f];
    tP += sv * wr[17408+tid];
  }
  red[tid] = sP; __syncthreads();
  for (int off=512; off>=32; off>>=1){
    if (tid<off) red[tid] += red[tid+off];
    __syncthreads();
  }
  if (tid<32) bp[(size_t)o*K1 + tid] = __float2bfloat16(red[tid]);
  __syncthreads();
  red[tid] = tP; __syncthreads();
  for (int off=512; off; off>>=1){
    if (tid<off) red[tid] += red[tid+off];
    __syncthreads();
  }
  if (tid==0) ws[WS_K+o] = red[0] + bc1[o];
  bp[(size_t)o*K1 + 32 + tid] = __float2bfloat16(wr[16384+tid]);
  if (tid < 512) w2b[o*512+tid] = __float2bfloat16(Wc2[o*512+tid]);
}

// ============ bf16 MFMA GEMM: C = A(MxK)·B(NxK)^T, 64x64 tile ==============
template<bool RELU, bool BF16OUT>
__global__ __launch_bounds__(256)
void gemm_mfma(const bf16* __restrict__ A, const bf16* __restrict__ B,
               const float* __restrict__ bias, float* __restrict__ Cf,
               bf16* __restrict__ Cb, int M, int N, int K){
  __shared__ short Als[2048];
  __shared__ short Bls[2048];
  const int tid = threadIdx.x;
  const int bm = blockIdx.y*64, bn = blockIdx.x*64;
  const int wave = tid>>6, lane = tid&63;
  const int wm = wave>>1, wn = wave&1;
  const int r = lane&15, q = lane>>4;
  f32x4 acc[2][2] = {};
  const int lrow = tid>>2, lq = tid&3;
  const bf16* Ag = A + (size_t)(bm+lrow)*K + lq*8;
  const bf16* Bg = B + (size_t)(bn+lrow)*K + lq*8;
  const int sidx = (lq*64+lrow)*8;
  for (int k0=0; k0<K; k0+=32){
    float4 av = *(const float4*)(Ag + k0);
    float4 bv = *(const float4*)(Bg + k0);
    *(float4*)(&Als[sidx]) = av;
    *(float4*)(&Bls[sidx]) = bv;
    __syncthreads();
    #pragma unroll
    for (int i=0;i<2;i++){
      bf16x8 af = *(const bf16x8*)(&Als[(q*64 + wm*32 + i*16 + r)*8]);
      #pragma unroll
      for (int j=0;j<2;j++){
        bf16x8 bfr = *(const bf16x8*)(&Bls[(q*64 + wn*32 + j*16 + r)*8]);
        acc[i][j] = __builtin_amdgcn_mfma_f32_16x16x32_bf16(af, bfr, acc[i][j], 0,0,0);
      }
    }
    __syncthreads();
  }
  #pragma unroll
  for (int i=0;i<2;i++){
    int row = bm + wm*32 + i*16 + q*4;
    #pragma unroll
    for (int j=0;j<2;j++){
      int col = bn + wn*32 + j*16 + r;
      float bi = bias ? bias[col] : 0.f;
      #pragma unroll
      for (int g=0; g<4; g++){
        float v = acc[i][j][g] + bi;
        if (RELU) v = fmaxf(v, 0.f);
        if (BF16OUT) Cb[(size_t)(row+g)*N + col] = __float2bfloat16(v);
        else         Cf[(size_t)(row+g)*N + col] = v;
      }
    }
  }
}

extern "C" void kernel_launch(void* const* d_in, const int* in_sizes, int n_in,
                              void* d_out, int out_size, void* d_ws, size_t ws_size,
                              hipStream_t stream){
  const float* dist   = (const float*)d_in[0];
  const float* markov = (const float*)d_in[1];
  const float* demand = (const float*)d_in[2];
  const float* Wweek  = (const float*)d_in[3];
  const float* Wcap   = (const float*)d_in[4];
  const float* Wveh   = (const float*)d_in[5];
  const float* g1W    = (const float*)d_in[6];
  const float* g1as   = (const float*)d_in[7];
  const float* g1ad   = (const float*)d_in[8];
  const float* g1We   = (const float*)d_in[9];
  const float* g1ae   = (const float*)d_in[10];
  const float* g1b    = (const float*)d_in[11];
  const float* g2W    = (const float*)d_in[12];
  const float* g2as   = (const float*)d_in[13];
  const float* g2ad   = (const float*)d_in[14];
  const float* g2We   = (const float*)d_in[15];
  const float* g2ae   = (const float*)d_in[16];
  const float* g2b    = (const float*)d_in[17];
  const float* Wes    = (const float*)d_in[18];
  const float* bes    = (const float*)d_in[19];
  const float* Wc1    = (const float*)d_in[20];
  const float* bc1    = (const float*)d_in[21];
  const float* Wc2    = (const float*)d_in[22];
  const float* bc2    = (const float*)d_in[23];
  const int*   stops  = (const int*)d_in[24];
  const int*   eidx   = (const int*)d_in[25];
  const int*   wd     = (const int*)d_in[26];
  const int*   vh     = (const int*)d_in[27];
  const int*   cp     = (const int*)d_in[28];
  float* out = (float*)d_out;
  float* ws = (float*)d_ws;

  // K1: all input-only prep
  k_prep<<<611,256,0,stream>>>(demand, g1W, g1as, g1ad, stops, Wes, dist,
                               g1We, g1ae, g2We, g2ae, g2W, g2as, g2ad, ws);
  // K2: GAT layer-1 aggregate (self-gathering) + h2 + logits-2 epilogue
  k_agg<1><<<512,256,0,stream>>>(ws+WS_H, ws+WS_ASRC, ws+WS_ADST, eidx, markov,
                                 ws+WS_AE, g1b, dist, ws);
  // K3: GAT layer-2 aggregate + uv + packA epilogue
  k_agg<2><<<512,256,0,stream>>>(ws+WS_H2, ws+WS_ASRC2, ws+WS_ADST2, eidx, markov,
                                 ws+WS_AE+8, g2b, dist, ws);
  // K4: sk + packB + Wc2->bf16
  k_skpack<<<512,1024,0,stream>>>(Wc1, bc1, bes, Wweek, Wcap, Wveh, wd, vh, cp, Wc2, ws);
  // K5/K6: decoder MFMA GEMMs
  gemm_mfma<true,true><<<dim3(8,8),256,0,stream>>>((const bf16*)(ws+WS_APACK), (const bf16*)(ws+WS_BPACK),
                                                   ws+WS_K, nullptr, (bf16*)(ws+WS_OUT1), 512, 512, K1);
  gemm_mfma<false,false><<<dim3(8,8),256,0,stream>>>((const bf16*)(ws+WS_OUT1), (const bf16*)(ws+WS_WC2B),
                                                     bc2, out, nullptr, 512, 512, 512);
}

// Round 11
// 207.757 us; speedup vs baseline: 1.0752x; 1.0752x over previous
//
#include <hip/hip_runtime.h>
#include <hip/hip_bf16.h>

typedef __hip_bfloat16 bf16;
typedef __attribute__((ext_vector_type(8))) short bf16x8;
typedef __attribute__((ext_vector_type(4))) float f32x4;

#define NNODE 512
#define NEDGE 16384
#define INLEN 17929
#define K1    1056

// ---- workspace layout (offsets in floats) ----
#define WS_EA      0         // 16384
#define WS_CSRC    16384     // 16384 (int)
#define WS_CEA     32768     // 16384
#define WS_DEG     49152     // 512 (int)
#define WS_STARTS  49664     // 512 (int)
#define WS_LATTR   50176     // 512
#define WS_MM      50688     // 2
#define WS_MMP     50690     // 128
#define WS_STOPV   50818     // 512
#define WS_AE      51330     // 16
#define WS_PS      51346     // 4096
#define WS_H       55552     // 512*256
#define WS_G2WT    186624    // 256*256
#define WS_H2      317696    // 512*256
#define WS_ASRC    448768    // 512*8
#define WS_ADST    452864    // 512*8
#define WS_UV      456960    // 512*64
#define WS_K       489728    // 512
#define WS_APACK   490240    // bf16 512*1056 -> 270336 floats
#define WS_BPACK   760576    // bf16 512*1056 -> 270336 floats
#define WS_OUT1    1030912   // bf16 512*512  -> 131072 floats
#define WS_WC2B    1161984   // bf16 512*512  -> 131072 floats
#define WS_WESF    1293056   // 64*256
#define WS_ASRC2   1309440   // 512*8
#define WS_ADST2   1313536   // 512*8
#define WS_CURSOR  1317632   // 512 (int)
#define WS_DEGP    1318144   // 64*512 (int)
#define WS_LSUMP   1350912   // 64*512
// end = 1383680 floats ≈ 5.5 MB

// ============ K1: fused prep (all input-only, fully parallel) ===============
__global__ __launch_bounds__(256)
void k_prep(const float* __restrict__ demand, const float* __restrict__ W1,
            const float* __restrict__ att_s, const float* __restrict__ att_d,
            const int* __restrict__ stops, const float* __restrict__ Wes,
            const float* __restrict__ dist, const float* __restrict__ markov,
            const int* __restrict__ eidx,
            const float* __restrict__ g1We, const float* __restrict__ g1ae,
            const float* __restrict__ g2We, const float* __restrict__ g2ae,
            const float* __restrict__ g2W,  const float* __restrict__ g2as,
            const float* __restrict__ g2ad, float* ws){
  int b = blockIdx.x, tid = threadIdx.x;
  if (b < 512){
    int hd = tid>>5, c = tid&31;
    float hv = demand[b] * W1[tid];
    ws[WS_H + b*256 + tid] = hv;
    float ps = hv * att_s[tid];
    float pd = hv * att_d[tid];
    for (int off=16; off; off>>=1){ ps += __shfl_down(ps,off,32); pd += __shfl_down(pd,off,32); }
    if (c==0){ ws[WS_ASRC + b*8+hd]=ps; ws[WS_ADST + b*8+hd]=pd; }
  } else if (b == 512){
    ws[WS_STOPV+tid] = 0.f; ws[WS_STOPV+256+tid] = 0.f;
    __syncthreads();
    ws[WS_STOPV + stops[tid]] = 1.0f;
    if (tid < 8){
      float s=0.f; for (int c=0;c<32;c++) s += g1We[tid*32+c]*g1ae[tid*32+c];
      ws[WS_AE+tid]=s;
    } else if (tid < 16){
      int h=tid-8; float s=0.f; for (int c=0;c<32;c++) s += g2We[h*32+c]*g2ae[h*32+c];
      ws[WS_AE+8+h]=s;
    }
  } else if (b < 515){
    for (int idx = (b-513)*8192 + tid; idx < (b-512)*8192; idx += 256){
      int k = idx>>8, c = idx&255;
      ws[WS_WESF+idx] = (k<32) ? Wes[k*512+c] : Wes[(k-32)*512+256+c];
    }
  } else if (b < 579){
    __shared__ float smn[256], smx[256];
    int p = b-515;
    float mn = 3.4e38f, mx = -3.4e38f;
    for (int k=0;k<16;k++){
      float v = dist[p*4096 + k*256 + tid];
      mn = fminf(mn,v); mx = fmaxf(mx,v);
    }
    smn[tid]=mn; smx[tid]=mx; __syncthreads();
    for (int off=128; off; off>>=1){
      if (tid<off){ smn[tid]=fminf(smn[tid],smn[tid+off]); smx[tid]=fmaxf(smx[tid],smx[tid+off]); }
      __syncthreads();
    }
    if (tid==0){ ws[WS_MMP+p]=smn[0]; ws[WS_MMP+64+p]=smx[0]; }
  } else if (b < 643){
    // ea gather + per-block partial histogram (LDS, no global atomics)
    __shared__ int   hd_[512];
    __shared__ float hf_[512];
    int k = b-579;
    hd_[tid]=0; hd_[256+tid]=0; hf_[tid]=0.f; hf_[256+tid]=0.f;
    __syncthreads();
    int e = k*256 + tid;
    int r = eidx[e], c = eidx[NEDGE+e];
    float a = markov[r*NNODE + c];
    ws[WS_EA+e] = a;
    atomicAdd(&hd_[c], 1);
    atomicAdd(&hf_[c], a);
    __syncthreads();
    ((int*)(ws+WS_DEGP))[k*512+tid]     = hd_[tid];
    ((int*)(ws+WS_DEGP))[k*512+256+tid] = hd_[256+tid];
    ws[WS_LSUMP + k*512+tid]     = hf_[tid];
    ws[WS_LSUMP + k*512+256+tid] = hf_[256+tid];
  } else if (b < 659){
    int j = b-643;
    const float* att = (j<8) ? g2as : g2ad;
    int h = j&7;
    float s = 0.f;
    for (int c=0;c<32;c++) s += att[h*32+c] * g2W[(h*32+c)*256 + tid];
    ws[WS_PS + j*256 + tid] = s;
  } else if (b < 675){
    __shared__ float T[64][65];
    int tb = b-659, tr = tb>>2, tc = tb&3;
    int w = tid>>6, c = tid&63;
    for (int k=0;k<16;k++){
      int r = k*4 + w;
      T[r][c] = g2W[(tr*64+r)*256 + tc*64 + c];
    }
    __syncthreads();
    for (int k=0;k<16;k++){
      int r = k*4 + w;
      ws[WS_G2WT + (tc*64+r)*256 + tr*64 + c] = T[c][r];
    }
  } else {
    ((int*)(ws+WS_CURSOR))[tid] = 0;
    ((int*)(ws+WS_CURSOR))[256+tid] = 0;
  }
}

// ============ K2: merged scan + scatter (32 blocks x 512 thr) ===============
__global__ __launch_bounds__(512)
void k_scansc(const int* __restrict__ eidx, float* ws){
  __shared__ int sc[512];
  __shared__ int startS[512];
  __shared__ float rmn[64], rmx[64];
  int t = threadIdx.x, b = blockIdx.x;
  const int* dp = (const int*)(ws+WS_DEGP);
  int d = 0;
  for (int k=0;k<64;k++) d += dp[k*512+t];
  sc[t] = d; __syncthreads();
  for (int off=1; off<512; off<<=1){
    int v = (t>=off) ? sc[t-off] : 0; __syncthreads();
    sc[t] += v; __syncthreads();
  }
  startS[t] = sc[t]-d;
  if (b == 0){
    float l = 0.f;
    for (int k=0;k<64;k++) l += ws[WS_LSUMP+k*512+t];
    ((int*)(ws+WS_STARTS))[t] = startS[t];
    ((int*)(ws+WS_DEG))[t] = d;
    ws[WS_LATTR+t] = l / (float)(d>1 ? d : 1);
    if (t < 64){ rmn[t]=ws[WS_MMP+t]; rmx[t]=ws[WS_MMP+64+t]; }
    __syncthreads();
    if (t == 0){
      float mn=rmn[0], mx=rmx[0];
      for (int i=1;i<64;i++){ mn=fminf(mn,rmn[i]); mx=fmaxf(mx,rmx[i]); }
      ws[WS_MM]=mn; ws[WS_MM+1]=mx;
    }
  }
  __syncthreads();
  int e = b*512 + t;
  int c = eidx[NEDGE+e];
  int p = startS[c] + atomicAdd((int*)(ws+WS_CURSOR)+c, 1);
  ((int*)(ws+WS_CSRC))[p] = eidx[e];
  ws[WS_CEA+p] = ws[WS_EA+e];
}

// ============ GAT aggregate: CSR edges, single-pass softmax =================
// MODE 1: +h2+logits2 epilogue | MODE 2: +uv+packA epilogue
template<int MODE>
__global__ __launch_bounds__(256)
void k_agg(const float* __restrict__ hbuf, const float* __restrict__ asrc,
           const float* __restrict__ adst, const int* __restrict__ csrc,
           const float* __restrict__ cea, const int* __restrict__ starts,
           const int* __restrict__ deg, const float* __restrict__ lattr,
           const float* __restrict__ AEp, const float* __restrict__ bvec,
           const float* __restrict__ dist, const float* __restrict__ markov,
           float* ws){
  int t = blockIdx.x, tid = threadIdx.x, hd = tid>>5;
  __shared__ int   srcE[256];
  __shared__ float eaE[256];
  __shared__ float Lall[256*8];
  __shared__ float AE[8], mh[8], dh[8], sw[8];
  __shared__ float xrow[256], uvrow[64];
  if (tid<8) AE[tid]=AEp[tid];
  __syncthreads();
  int d = deg[t], s0 = starts[t];
  if (d > 256) d = 256;                     // statistically impossible; safety
  // stage edges (coalesced CSR reads)
  for (int e=tid; e<d; e+=256){ srcE[e]=csrc[s0+e]; eaE[e]=cea[s0+e]; }
  __syncthreads();
  // all edge logits -> LDS
  {
    int h8 = tid&7;
    float adt = adst[t*8+h8], aeh = AE[h8];
    for (int e = tid>>3; e < d; e += 32){
      float a = asrc[srcE[e]*8+h8] + adt + eaE[e]*aeh;
      Lall[e*8+h8] = a>=0.f ? a : 0.2f*a;
    }
  }
  __syncthreads();
  // per-head max / denom (32 lanes per head, shuffle reduce)
  {
    int h = tid>>5, j = tid&31;
    float aself = asrc[t*8+h] + adst[t*8+h] + lattr[t]*AE[h];
    aself = aself>=0.f ? aself : 0.2f*aself;
    float mm = aself;
    for (int e=j; e<d; e+=32) mm = fmaxf(mm, Lall[e*8+h]);
    for (int off=16; off; off>>=1) mm = fmaxf(mm, __shfl_down(mm,off,32));
    mm = __shfl(mm, 0, 32);
    float dd = 0.f;
    for (int e=j; e<d; e+=32) dd += __expf(Lall[e*8+h]-mm);
    for (int off=16; off; off>>=1) dd += __shfl_down(dd,off,32);
    if (j==0){
      float se = __expf(aself-mm);
      mh[h]=mm; dh[h]=dd+se+1e-16f; sw[h]=se;
    }
  }
  __syncthreads();
  // logits -> unnormalized weights
  {
    int h8 = tid&7;
    for (int e = tid>>3; e < d; e += 32)
      Lall[e*8+h8] = __expf(Lall[e*8+h8] - mh[h8]);
  }
  __syncthreads();
  // gather-accumulate (4-way ILP)
  float a0 = sw[hd]*hbuf[t*256+tid], a1=0.f, a2=0.f, a3=0.f;
  int e = 0;
  for (; e+4<=d; e+=4){
    a0 += Lall[(e+0)*8+hd]*hbuf[srcE[e+0]*256+tid];
    a1 += Lall[(e+1)*8+hd]*hbuf[srcE[e+1]*256+tid];
    a2 += Lall[(e+2)*8+hd]*hbuf[srcE[e+2]*256+tid];
    a3 += Lall[(e+3)*8+hd]*hbuf[srcE[e+3]*256+tid];
  }
  for (; e<d; e++) a0 += Lall[e*8+hd]*hbuf[srcE[e]*256+tid];
  float v = fmaxf(((a0+a1)+(a2+a3))/dh[hd] + bvec[tid], 0.f);
  xrow[tid] = v;
  __syncthreads();
  if (MODE == 1){
    const float* g2wt = ws + WS_G2WT;
    float h0=0.f,h1=0.f,h2=0.f,h3=0.f;
    for (int c=0;c<256;c+=4){
      h0 += xrow[c+0]*g2wt[(c+0)*256+tid];
      h1 += xrow[c+1]*g2wt[(c+1)*256+tid];
      h2 += xrow[c+2]*g2wt[(c+2)*256+tid];
      h3 += xrow[c+3]*g2wt[(c+3)*256+tid];
    }
    ws[WS_H2 + t*256 + tid] = (h0+h1)+(h2+h3);
    if (tid < 64){
      int j = tid>>2, q = tid&3;
      const float* pr = ws + WS_PS + j*256 + q*64;
      const float* xr = xrow + q*64;
      float p = 0.f;
      for (int c=0;c<64;c++) p += xr[c]*pr[c];
      p += __shfl_down(p,2,4);
      p += __shfl_down(p,1,4);
      if (q==0){
        if (j<8) ws[WS_ASRC2 + t*8+j] = p;
        else     ws[WS_ADST2 + t*8+(j-8)] = p;
      }
    }
  } else {
    int k = tid>>2, q = tid&3;
    const float* wr = ws + WS_WESF + k*256 + q*64;
    const float* xr = xrow + q*64;
    float p = 0.f;
    for (int c=0;c<64;c++) p += xr[c]*wr[c];
    p += __shfl_down(p,2,4);
    p += __shfl_down(p,1,4);
    if (q==0){ ws[WS_UV + t*64+k] = p; uvrow[k] = p; }
    __syncthreads();
    float mn = ws[WS_MM], mx = ws[WS_MM+1];
    float inv = 1.0f/(mx-mn);
    bf16* ap = (bf16*)(ws+WS_APACK);
    const float* mrow = markov + t*512;
    for (int j=tid; j<K1; j+=256){
      float v2;
      if (j<32)       v2 = uvrow[j];
      else if (j<544) v2 = (dist[t*512 + j-32] - mn) * inv;
      else            v2 = mrow[j-544];
      ap[(size_t)t*K1 + j] = __float2bfloat16(v2);
    }
  }
}

// ============ K5: sk+packB + Wc2->bf16 — 1024 thr, 4-way ILP ================
__global__ __launch_bounds__(1024)
void k_skpack(const float* __restrict__ Wc1, const float* __restrict__ bc1,
              const float* __restrict__ bes, const float* __restrict__ Wweek,
              const float* __restrict__ Wcap, const float* __restrict__ Wveh,
              const int* __restrict__ wd, const int* __restrict__ vh,
              const int* __restrict__ cp, const float* __restrict__ Wc2,
              float* ws){
  int o = blockIdx.x, tid = threadIdx.x;
  __shared__ float besf[32];
  __shared__ float red[1024];
  if (tid<32) besf[tid] = bes[tid];
  __syncthreads();
  const float* wr = Wc1 + (size_t)o*INLEN;
  bf16* bp  = (bf16*)(ws+WS_BPACK);
  bf16* w2b = (bf16*)(ws+WS_WC2B);
  float be = besf[tid&31];
  const float* uvp = ws + WS_UV + ((tid>>5)<<6) + 32 + (tid&31);
  float sP = 0.f, tP0=0.f, tP1=0.f, tP2=0.f, tP3=0.f;
  #pragma unroll
  for (int i=0;i<16;i+=4){
    float w0 = wr[tid + 1024*(i+0)];
    float w1 = wr[tid + 1024*(i+1)];
    float w2 = wr[tid + 1024*(i+2)];
    float w3 = wr[tid + 1024*(i+3)];
    float u0 = uvp[2048*(i+0)];
    float u1 = uvp[2048*(i+1)];
    float u2 = uvp[2048*(i+2)];
    float u3 = uvp[2048*(i+3)];
    sP += (w0+w1)+(w2+w3);
    tP0 += w0*(u0+be);
    tP1 += w1*(u1+be);
    tP2 += w2*(u2+be);
    tP3 += w3*(u3+be);
  }
  float tP = (tP0+tP1)+(tP2+tP3);
  if (tid < 512) tP += ws[WS_STOPV+tid] * wr[17417+tid];
  if (tid < 9){
    int g = tid/3, f = tid-g*3;
    float sv = (g==0) ? Wweek[wd[0]*3+f]
             : (g==1) ? Wcap[cp[0]*3+f]
                      : Wveh[vh[0]*3+f];
    tP += sv * wr[17408+tid];
  }
  red[tid] = sP; __syncthreads();
  for (int off=512; off>=32; off>>=1){
    if (tid<off) red[tid] += red[tid+off];
    __syncthreads();
  }
  if (tid<32) bp[(size_t)o*K1 + tid] = __float2bfloat16(red[tid]);
  __syncthreads();
  red[tid] = tP; __syncthreads();
  for (int off=512; off; off>>=1){
    if (tid<off) red[tid] += red[tid+off];
    __syncthreads();
  }
  if (tid==0) ws[WS_K+o] = red[0] + bc1[o];
  bp[(size_t)o*K1 + 32 + tid] = __float2bfloat16(wr[16384+tid]);
  if (tid < 512) w2b[o*512+tid] = __float2bfloat16(Wc2[o*512+tid]);
}

// ============ bf16 MFMA GEMM: C = A(MxK)·B(NxK)^T, 64x64 tile ==============
template<bool RELU, bool BF16OUT>
__global__ __launch_bounds__(256)
void gemm_mfma(const bf16* __restrict__ A, const bf16* __restrict__ B,
               const float* __restrict__ bias, float* __restrict__ Cf,
               bf16* __restrict__ Cb, int M, int N, int K){
  __shared__ short Als[2048];
  __shared__ short Bls[2048];
  const int tid = threadIdx.x;
  const int bm = blockIdx.y*64, bn = blockIdx.x*64;
  const int wave = tid>>6, lane = tid&63;
  const int wm = wave>>1, wn = wave&1;
  const int r = lane&15, q = lane>>4;
  f32x4 acc[2][2] = {};
  const int lrow = tid>>2, lq = tid&3;
  const bf16* Ag = A + (size_t)(bm+lrow)*K + lq*8;
  const bf16* Bg = B + (size_t)(bn+lrow)*K + lq*8;
  const int sidx = (lq*64+lrow)*8;
  for (int k0=0; k0<K; k0+=32){
    float4 av = *(const float4*)(Ag + k0);
    float4 bv = *(const float4*)(Bg + k0);
    *(float4*)(&Als[sidx]) = av;
    *(float4*)(&Bls[sidx]) = bv;
    __syncthreads();
    #pragma unroll
    for (int i=0;i<2;i++){
      bf16x8 af = *(const bf16x8*)(&Als[(q*64 + wm*32 + i*16 + r)*8]);
      #pragma unroll
      for (int j=0;j<2;j++){
        bf16x8 bfr = *(const bf16x8*)(&Bls[(q*64 + wn*32 + j*16 + r)*8]);
        acc[i][j] = __builtin_amdgcn_mfma_f32_16x16x32_bf16(af, bfr, acc[i][j], 0,0,0);
      }
    }
    __syncthreads();
  }
  #pragma unroll
  for (int i=0;i<2;i++){
    int row = bm + wm*32 + i*16 + q*4;
    #pragma unroll
    for (int j=0;j<2;j++){
      int col = bn + wn*32 + j*16 + r;
      float bi = bias ? bias[col] : 0.f;
      #pragma unroll
      for (int g=0; g<4; g++){
        float v = acc[i][j][g] + bi;
        if (RELU) v = fmaxf(v, 0.f);
        if (BF16OUT) Cb[(size_t)(row+g)*N + col] = __float2bfloat16(v);
        else         Cf[(size_t)(row+g)*N + col] = v;
      }
    }
  }
}

extern "C" void kernel_launch(void* const* d_in, const int* in_sizes, int n_in,
                              void* d_out, int out_size, void* d_ws, size_t ws_size,
                              hipStream_t stream){
  const float* dist   = (const float*)d_in[0];
  const float* markov = (const float*)d_in[1];
  const float* demand = (const float*)d_in[2];
  const float* Wweek  = (const float*)d_in[3];
  const float* Wcap   = (const float*)d_in[4];
  const float* Wveh   = (const float*)d_in[5];
  const float* g1W    = (const float*)d_in[6];
  const float* g1as   = (const float*)d_in[7];
  const float* g1ad   = (const float*)d_in[8];
  const float* g1We   = (const float*)d_in[9];
  const float* g1ae   = (const float*)d_in[10];
  const float* g1b    = (const float*)d_in[11];
  const float* g2W    = (const float*)d_in[12];
  const float* g2as   = (const float*)d_in[13];
  const float* g2ad   = (const float*)d_in[14];
  const float* g2We   = (const float*)d_in[15];
  const float* g2ae   = (const float*)d_in[16];
  const float* g2b    = (const float*)d_in[17];
  const float* Wes    = (const float*)d_in[18];
  const float* bes    = (const float*)d_in[19];
  const float* Wc1    = (const float*)d_in[20];
  const float* bc1    = (const float*)d_in[21];
  const float* Wc2    = (const float*)d_in[22];
  const float* bc2    = (const float*)d_in[23];
  const int*   stops  = (const int*)d_in[24];
  const int*   eidx   = (const int*)d_in[25];
  const int*   wd     = (const int*)d_in[26];
  const int*   vh     = (const int*)d_in[27];
  const int*   cp     = (const int*)d_in[28];
  float* out = (float*)d_out;
  float* ws = (float*)d_ws;

  const int*   csrc   = (const int*)(ws+WS_CSRC);
  const float* cea    = ws+WS_CEA;
  const int*   starts = (const int*)(ws+WS_STARTS);
  const int*   deg    = (const int*)(ws+WS_DEG);
  const float* lattr  = ws+WS_LATTR;

  // K1: all input-only prep (+ histogram partials, cursor zero)
  k_prep<<<676,256,0,stream>>>(demand, g1W, g1as, g1ad, stops, Wes, dist, markov, eidx,
                               g1We, g1ae, g2We, g2ae, g2W, g2as, g2ad, ws);
  // K2: merged scan + scatter
  k_scansc<<<32,512,0,stream>>>(eidx, ws);
  // K3: GAT layer-1 aggregate (single-pass softmax) + h2 + logits-2 epilogue
  k_agg<1><<<512,256,0,stream>>>(ws+WS_H, ws+WS_ASRC, ws+WS_ADST, csrc, cea, starts, deg,
                                 lattr, ws+WS_AE, g1b, dist, markov, ws);
  // K4: GAT layer-2 aggregate + uv + packA epilogue
  k_agg<2><<<512,256,0,stream>>>(ws+WS_H2, ws+WS_ASRC2, ws+WS_ADST2, csrc, cea, starts, deg,
                                 lattr, ws+WS_AE+8, g2b, dist, markov, ws);
  // K5: sk + packB + Wc2->bf16 (1024 threads, ILP-unrolled)
  k_skpack<<<512,1024,0,stream>>>(Wc1, bc1, bes, Wweek, Wcap, Wveh, wd, vh, cp, Wc2, ws);
  // K6/K7: decoder MFMA GEMMs
  gemm_mfma<true,true><<<dim3(8,8),256,0,stream>>>((const bf16*)(ws+WS_APACK), (const bf16*)(ws+WS_BPACK),
                                                   ws+WS_K, nullptr, (bf16*)(ws+WS_OUT1), 512, 512, K1);
  gemm_mfma<false,false><<<dim3(8,8),256,0,stream>>>((const bf16*)(ws+WS_OUT1), (const bf16*)(ws+WS_WC2B),
                                                     bc2, out, nullptr, 512, 512, 512);
}

// Round 12
// 204.520 us; speedup vs baseline: 1.0923x; 1.0158x over previous
//
#include <hip/hip_runtime.h>
#include <hip/hip_bf16.h>

typedef __hip_bfloat16 bf16;
typedef __attribute__((ext_vector_type(8))) short bf16x8;
typedef __attribute__((ext_vector_type(4))) float f32x4;

#define NNODE 512
#define NEDGE 16384
#define INLEN 17929
#define K1    1056

// ---- workspace layout (offsets in floats) ----
#define WS_EA      0         // 16384
#define WS_CSRC    16384     // 16384 (int)
#define WS_CEA     32768     // 16384
#define WS_DEG     49152     // 512 (int)
#define WS_STARTS  49664     // 512 (int)
#define WS_LATTR   50176     // 512
#define WS_MM      50688     // 2
#define WS_MMP     50690     // 128
#define WS_STOPV   50818     // 512
#define WS_AE      51330     // 16
#define WS_PS      51346     // 4096
#define WS_H       55552     // 512*256
#define WS_G2WT    186624    // 256*256
#define WS_H2      317696    // 512*256
#define WS_ASRC    448768    // 512*8
#define WS_ADST    452864    // 512*8
#define WS_UV      456960    // 512*64
#define WS_K       489728    // 512
#define WS_APACK   490240    // bf16 512*1056 -> 270336 floats
#define WS_BPACK   760576    // bf16 512*1056 -> 270336 floats
#define WS_OUT1    1030912   // bf16 512*512  -> 131072 floats
#define WS_WC2B    1161984   // bf16 512*512  -> 131072 floats
#define WS_WESF    1293056   // 64*256
#define WS_ASRC2   1309440   // 512*8
#define WS_ADST2   1313536   // 512*8
#define WS_CURSOR  1317632   // 512 (int)
#define WS_DEGP    1318144   // 64*512 (int)
#define WS_LSUMP   1350912   // 64*512
// end = 1383680 floats ≈ 5.5 MB

// ============ K1: fused prep (all input-only, fully parallel) ===============
__global__ __launch_bounds__(256)
void k_prep(const float* __restrict__ demand, const float* __restrict__ W1,
            const float* __restrict__ att_s, const float* __restrict__ att_d,
            const int* __restrict__ stops, const float* __restrict__ Wes,
            const float* __restrict__ dist, const float* __restrict__ markov,
            const int* __restrict__ eidx,
            const float* __restrict__ g1We, const float* __restrict__ g1ae,
            const float* __restrict__ g2We, const float* __restrict__ g2ae,
            const float* __restrict__ g2W,  const float* __restrict__ g2as,
            const float* __restrict__ g2ad, float* ws){
  int b = blockIdx.x, tid = threadIdx.x;
  if (b < 512){
    int hd = tid>>5, c = tid&31;
    float hv = demand[b] * W1[tid];
    ws[WS_H + b*256 + tid] = hv;
    float ps = hv * att_s[tid];
    float pd = hv * att_d[tid];
    for (int off=16; off; off>>=1){ ps += __shfl_down(ps,off,32); pd += __shfl_down(pd,off,32); }
    if (c==0){ ws[WS_ASRC + b*8+hd]=ps; ws[WS_ADST + b*8+hd]=pd; }
  } else if (b == 512){
    ws[WS_STOPV+tid] = 0.f; ws[WS_STOPV+256+tid] = 0.f;
    __syncthreads();
    ws[WS_STOPV + stops[tid]] = 1.0f;
    if (tid < 8){
      float s=0.f; for (int c=0;c<32;c++) s += g1We[tid*32+c]*g1ae[tid*32+c];
      ws[WS_AE+tid]=s;
    } else if (tid < 16){
      int h=tid-8; float s=0.f; for (int c=0;c<32;c++) s += g2We[h*32+c]*g2ae[h*32+c];
      ws[WS_AE+8+h]=s;
    }
  } else if (b < 515){
    for (int idx = (b-513)*8192 + tid; idx < (b-512)*8192; idx += 256){
      int k = idx>>8, c = idx&255;
      ws[WS_WESF+idx] = (k<32) ? Wes[k*512+c] : Wes[(k-32)*512+256+c];
    }
  } else if (b < 579){
    __shared__ float smn[256], smx[256];
    int p = b-515;
    float mn = 3.4e38f, mx = -3.4e38f;
    const float4* dv = (const float4*)(dist + p*4096);
    #pragma unroll
    for (int k=0;k<4;k++){
      float4 v = dv[k*256 + tid];
      mn = fminf(mn, fminf(fminf(v.x,v.y), fminf(v.z,v.w)));
      mx = fmaxf(mx, fmaxf(fmaxf(v.x,v.y), fmaxf(v.z,v.w)));
    }
    smn[tid]=mn; smx[tid]=mx; __syncthreads();
    for (int off=128; off; off>>=1){
      if (tid<off){ smn[tid]=fminf(smn[tid],smn[tid+off]); smx[tid]=fmaxf(smx[tid],smx[tid+off]); }
      __syncthreads();
    }
    if (tid==0){ ws[WS_MMP+p]=smn[0]; ws[WS_MMP+64+p]=smx[0]; }
  } else if (b < 643){
    // ea gather + per-block partial histogram (LDS, no global atomics)
    __shared__ int   hd_[512];
    __shared__ float hf_[512];
    int k = b-579;
    hd_[tid]=0; hd_[256+tid]=0; hf_[tid]=0.f; hf_[256+tid]=0.f;
    __syncthreads();
    int e = k*256 + tid;
    int r = eidx[e], c = eidx[NEDGE+e];
    float a = markov[r*NNODE + c];
    ws[WS_EA+e] = a;
    atomicAdd(&hd_[c], 1);
    atomicAdd(&hf_[c], a);
    __syncthreads();
    ((int*)(ws+WS_DEGP))[k*512+tid]     = hd_[tid];
    ((int*)(ws+WS_DEGP))[k*512+256+tid] = hd_[256+tid];
    ws[WS_LSUMP + k*512+tid]     = hf_[tid];
    ws[WS_LSUMP + k*512+256+tid] = hf_[256+tid];
  } else if (b < 659){
    int j = b-643;
    const float* att = (j<8) ? g2as : g2ad;
    int h = j&7;
    float s = 0.f;
    for (int c=0;c<32;c++) s += att[h*32+c] * g2W[(h*32+c)*256 + tid];
    ws[WS_PS + j*256 + tid] = s;
  } else if (b < 675){
    __shared__ float T[64][65];
    int tb = b-659, tr = tb>>2, tc = tb&3;
    int w = tid>>6, c = tid&63;
    for (int k=0;k<16;k++){
      int r = k*4 + w;
      T[r][c] = g2W[(tr*64+r)*256 + tc*64 + c];
    }
    __syncthreads();
    for (int k=0;k<16;k++){
      int r = k*4 + w;
      ws[WS_G2WT + (tc*64+r)*256 + tr*64 + c] = T[c][r];
    }
  } else {
    ((int*)(ws+WS_CURSOR))[tid] = 0;
    ((int*)(ws+WS_CURSOR))[256+tid] = 0;
  }
}

// ============ K2: merged scan + scatter (32 blocks x 512 thr) ===============
__global__ __launch_bounds__(512)
void k_scansc(const int* __restrict__ eidx, float* ws){
  __shared__ int sc[512];
  __shared__ int startS[512];
  __shared__ float rmn[64], rmx[64];
  int t = threadIdx.x, b = blockIdx.x;
  const int* dp = (const int*)(ws+WS_DEGP);
  int d = 0;
  for (int k=0;k<64;k++) d += dp[k*512+t];
  sc[t] = d; __syncthreads();
  for (int off=1; off<512; off<<=1){
    int v = (t>=off) ? sc[t-off] : 0; __syncthreads();
    sc[t] += v; __syncthreads();
  }
  startS[t] = sc[t]-d;
  if (b == 0){
    float l = 0.f;
    for (int k=0;k<64;k++) l += ws[WS_LSUMP+k*512+t];
    ((int*)(ws+WS_STARTS))[t] = startS[t];
    ((int*)(ws+WS_DEG))[t] = d;
    ws[WS_LATTR+t] = l / (float)(d>1 ? d : 1);
    if (t < 64){ rmn[t]=ws[WS_MMP+t]; rmx[t]=ws[WS_MMP+64+t]; }
    __syncthreads();
    if (t == 0){
      float mn=rmn[0], mx=rmx[0];
      for (int i=1;i<64;i++){ mn=fminf(mn,rmn[i]); mx=fmaxf(mx,rmx[i]); }
      ws[WS_MM]=mn; ws[WS_MM+1]=mx;
    }
  }
  __syncthreads();
  int e = b*512 + t;
  int c = eidx[NEDGE+e];
  int p = startS[c] + atomicAdd((int*)(ws+WS_CURSOR)+c, 1);
  ((int*)(ws+WS_CSRC))[p] = eidx[e];
  ws[WS_CEA+p] = ws[WS_EA+e];
}

// ============ GAT aggregate: CSR edges, single-pass softmax =================
template<int MODE>
__global__ __launch_bounds__(256)
void k_agg(const float* __restrict__ hbuf, const float* __restrict__ asrc,
           const float* __restrict__ adst, const int* __restrict__ csrc,
           const float* __restrict__ cea, const int* __restrict__ starts,
           const int* __restrict__ deg, const float* __restrict__ lattr,
           const float* __restrict__ AEp, const float* __restrict__ bvec,
           const float* __restrict__ dist, const float* __restrict__ markov,
           float* ws){
  int t = blockIdx.x, tid = threadIdx.x, hd = tid>>5;
  __shared__ int   srcE[256];
  __shared__ float eaE[256];
  __shared__ float Lall[256*8];
  __shared__ float AE[8], mh[8], dh[8], sw[8];
  __shared__ float xrow[256], uvrow[64];
  if (tid<8) AE[tid]=AEp[tid];
  __syncthreads();
  int d = deg[t], s0 = starts[t];
  if (d > 256) d = 256;
  for (int e=tid; e<d; e+=256){ srcE[e]=csrc[s0+e]; eaE[e]=cea[s0+e]; }
  __syncthreads();
  {
    int h8 = tid&7;
    float adt = adst[t*8+h8], aeh = AE[h8];
    for (int e = tid>>3; e < d; e += 32){
      float a = asrc[srcE[e]*8+h8] + adt + eaE[e]*aeh;
      Lall[e*8+h8] = a>=0.f ? a : 0.2f*a;
    }
  }
  __syncthreads();
  {
    int h = tid>>5, j = tid&31;
    float aself = asrc[t*8+h] + adst[t*8+h] + lattr[t]*AE[h];
    aself = aself>=0.f ? aself : 0.2f*aself;
    float mm = aself;
    for (int e=j; e<d; e+=32) mm = fmaxf(mm, Lall[e*8+h]);
    for (int off=16; off; off>>=1) mm = fmaxf(mm, __shfl_down(mm,off,32));
    mm = __shfl(mm, 0, 32);
    float dd = 0.f;
    for (int e=j; e<d; e+=32) dd += __expf(Lall[e*8+h]-mm);
    for (int off=16; off; off>>=1) dd += __shfl_down(dd,off,32);
    if (j==0){
      float se = __expf(aself-mm);
      mh[h]=mm; dh[h]=dd+se+1e-16f; sw[h]=se;
    }
  }
  __syncthreads();
  {
    int h8 = tid&7;
    for (int e = tid>>3; e < d; e += 32)
      Lall[e*8+h8] = __expf(Lall[e*8+h8] - mh[h8]);
  }
  __syncthreads();
  float a0 = sw[hd]*hbuf[t*256+tid], a1=0.f, a2=0.f, a3=0.f;
  int e = 0;
  for (; e+4<=d; e+=4){
    a0 += Lall[(e+0)*8+hd]*hbuf[srcE[e+0]*256+tid];
    a1 += Lall[(e+1)*8+hd]*hbuf[srcE[e+1]*256+tid];
    a2 += Lall[(e+2)*8+hd]*hbuf[srcE[e+2]*256+tid];
    a3 += Lall[(e+3)*8+hd]*hbuf[srcE[e+3]*256+tid];
  }
  for (; e<d; e++) a0 += Lall[e*8+hd]*hbuf[srcE[e]*256+tid];
  float v = fmaxf(((a0+a1)+(a2+a3))/dh[hd] + bvec[tid], 0.f);
  xrow[tid] = v;
  __syncthreads();
  if (MODE == 1){
    const float* g2wt = ws + WS_G2WT;
    float h0=0.f,h1=0.f,h2=0.f,h3=0.f;
    for (int c=0;c<256;c+=4){
      h0 += xrow[c+0]*g2wt[(c+0)*256+tid];
      h1 += xrow[c+1]*g2wt[(c+1)*256+tid];
      h2 += xrow[c+2]*g2wt[(c+2)*256+tid];
      h3 += xrow[c+3]*g2wt[(c+3)*256+tid];
    }
    ws[WS_H2 + t*256 + tid] = (h0+h1)+(h2+h3);
    if (tid < 64){
      int j = tid>>2, q = tid&3;
      const float* pr = ws + WS_PS + j*256 + q*64;
      const float* xr = xrow + q*64;
      float p = 0.f;
      for (int c=0;c<64;c++) p += xr[c]*pr[c];
      p += __shfl_down(p,2,4);
      p += __shfl_down(p,1,4);
      if (q==0){
        if (j<8) ws[WS_ASRC2 + t*8+j] = p;
        else     ws[WS_ADST2 + t*8+(j-8)] = p;
      }
    }
  } else {
    int k = tid>>2, q = tid&3;
    const float* wr = ws + WS_WESF + k*256 + q*64;
    const float* xr = xrow + q*64;
    float p = 0.f;
    for (int c=0;c<64;c++) p += xr[c]*wr[c];
    p += __shfl_down(p,2,4);
    p += __shfl_down(p,1,4);
    if (q==0){ ws[WS_UV + t*64+k] = p; uvrow[k] = p; }
    __syncthreads();
    float mn = ws[WS_MM], mx = ws[WS_MM+1];
    float inv = 1.0f/(mx-mn);
    bf16* ap = (bf16*)(ws+WS_APACK);
    const float* mrow = markov + t*512;
    for (int j=tid; j<K1; j+=256){
      float v2;
      if (j<32)       v2 = uvrow[j];
      else if (j<544) v2 = (dist[t*512 + j-32] - mn) * inv;
      else            v2 = mrow[j-544];
      ap[(size_t)t*K1 + j] = __float2bfloat16(v2);
    }
  }
}

// ============ K5: sk+packB + Wc2->bf16 — 1024 thr, 4-way ILP ================
__global__ __launch_bounds__(1024)
void k_skpack(const float* __restrict__ Wc1, const float* __restrict__ bc1,
              const float* __restrict__ bes, const float* __restrict__ Wweek,
              const float* __restrict__ Wcap, const float* __restrict__ Wveh,
              const int* __restrict__ wd, const int* __restrict__ vh,
              const int* __restrict__ cp, const float* __restrict__ Wc2,
              float* ws){
  int o = blockIdx.x, tid = threadIdx.x;
  __shared__ float besf[32];
  __shared__ float red[1024];
  if (tid<32) besf[tid] = bes[tid];
  __syncthreads();
  const float* wr = Wc1 + (size_t)o*INLEN;
  bf16* bp  = (bf16*)(ws+WS_BPACK);
  bf16* w2b = (bf16*)(ws+WS_WC2B);
  float be = besf[tid&31];
  const float* uvp = ws + WS_UV + ((tid>>5)<<6) + 32 + (tid&31);
  float sP = 0.f, tP0=0.f, tP1=0.f, tP2=0.f, tP3=0.f;
  #pragma unroll
  for (int i=0;i<16;i+=4){
    float w0 = wr[tid + 1024*(i+0)];
    float w1 = wr[tid + 1024*(i+1)];
    float w2 = wr[tid + 1024*(i+2)];
    float w3 = wr[tid + 1024*(i+3)];
    float u0 = uvp[2048*(i+0)];
    float u1 = uvp[2048*(i+1)];
    float u2 = uvp[2048*(i+2)];
    float u3 = uvp[2048*(i+3)];
    sP += (w0+w1)+(w2+w3);
    tP0 += w0*(u0+be);
    tP1 += w1*(u1+be);
    tP2 += w2*(u2+be);
    tP3 += w3*(u3+be);
  }
  float tP = (tP0+tP1)+(tP2+tP3);
  if (tid < 512) tP += ws[WS_STOPV+tid] * wr[17417+tid];
  if (tid < 9){
    int g = tid/3, f = tid-g*3;
    float sv = (g==0) ? Wweek[wd[0]*3+f]
             : (g==1) ? Wcap[cp[0]*3+f]
                      : Wveh[vh[0]*3+f];
    tP += sv * wr[17408+tid];
  }
  red[tid] = sP; __syncthreads();
  for (int off=512; off>=32; off>>=1){
    if (tid<off) red[tid] += red[tid+off];
    __syncthreads();
  }
  if (tid<32) bp[(size_t)o*K1 + tid] = __float2bfloat16(red[tid]);
  __syncthreads();
  red[tid] = tP; __syncthreads();
  for (int off=512; off; off>>=1){
    if (tid<off) red[tid] += red[tid+off];
    __syncthreads();
  }
  if (tid==0) ws[WS_K+o] = red[0] + bc1[o];
  bp[(size_t)o*K1 + 32 + tid] = __float2bfloat16(wr[16384+tid]);
  if (tid < 512) w2b[o*512+tid] = __float2bfloat16(Wc2[o*512+tid]);
}

// ====== bf16 MFMA GEMM, 64x64 tile, double-buffered LDS + reg prefetch ======
template<bool RELU, bool BF16OUT>
__global__ __launch_bounds__(256)
void gemm_mfma(const bf16* __restrict__ A, const bf16* __restrict__ B,
               const float* __restrict__ bias, float* __restrict__ Cf,
               bf16* __restrict__ Cb, int M, int N, int K){
  __shared__ short Als[2][2048];
  __shared__ short Bls[2][2048];
  const int tid = threadIdx.x;
  const int bm = blockIdx.y*64, bn = blockIdx.x*64;
  const int wave = tid>>6, lane = tid&63;
  const int wm = wave>>1, wn = wave&1;
  const int r = lane&15, q = lane>>4;
  f32x4 acc[2][2] = {};
  const int lrow = tid>>2, lq = tid&3;
  const bf16* Ag = A + (size_t)(bm+lrow)*K + lq*8;
  const bf16* Bg = B + (size_t)(bn+lrow)*K + lq*8;
  const int sidx = (lq*64+lrow)*8;
  const int nk = K>>5;
  float4 av = *(const float4*)(Ag);
  float4 bv = *(const float4*)(Bg);
  *(float4*)(&Als[0][sidx]) = av;
  *(float4*)(&Bls[0][sidx]) = bv;
  __syncthreads();
  for (int kk=0; kk<nk; kk++){
    int cur = kk&1, nxt = cur^1;
    if (kk+1 < nk){
      av = *(const float4*)(Ag + (kk+1)*32);   // issue early; waits overlap MFMA
      bv = *(const float4*)(Bg + (kk+1)*32);
    }
    #pragma unroll
    for (int i=0;i<2;i++){
      bf16x8 af = *(const bf16x8*)(&Als[cur][(q*64 + wm*32 + i*16 + r)*8]);
      #pragma unroll
      for (int j=0;j<2;j++){
        bf16x8 bfr = *(const bf16x8*)(&Bls[cur][(q*64 + wn*32 + j*16 + r)*8]);
        acc[i][j] = __builtin_amdgcn_mfma_f32_16x16x32_bf16(af, bfr, acc[i][j], 0,0,0);
      }
    }
    if (kk+1 < nk){
      __syncthreads();
      *(float4*)(&Als[nxt][sidx]) = av;
      *(float4*)(&Bls[nxt][sidx]) = bv;
      __syncthreads();
    }
  }
  #pragma unroll
  for (int i=0;i<2;i++){
    int row = bm + wm*32 + i*16 + q*4;
    #pragma unroll
    for (int j=0;j<2;j++){
      int col = bn + wn*32 + j*16 + r;
      float bi = bias ? bias[col] : 0.f;
      #pragma unroll
      for (int g=0; g<4; g++){
        float v = acc[i][j][g] + bi;
        if (RELU) v = fmaxf(v, 0.f);
        if (BF16OUT) Cb[(size_t)(row+g)*N + col] = __float2bfloat16(v);
        else         Cf[(size_t)(row+g)*N + col] = v;
      }
    }
  }
}

extern "C" void kernel_launch(void* const* d_in, const int* in_sizes, int n_in,
                              void* d_out, int out_size, void* d_ws, size_t ws_size,
                              hipStream_t stream){
  const float* dist   = (const float*)d_in[0];
  const float* markov = (const float*)d_in[1];
  const float* demand = (const float*)d_in[2];
  const float* Wweek  = (const float*)d_in[3];
  const float* Wcap   = (const float*)d_in[4];
  const float* Wveh   = (const float*)d_in[5];
  const float* g1W    = (const float*)d_in[6];
  const float* g1as   = (const float*)d_in[7];
  const float* g1ad   = (const float*)d_in[8];
  const float* g1We   = (const float*)d_in[9];
  const float* g1ae   = (const float*)d_in[10];
  const float* g1b    = (const float*)d_in[11];
  const float* g2W    = (const float*)d_in[12];
  const float* g2as   = (const float*)d_in[13];
  const float* g2ad   = (const float*)d_in[14];
  const float* g2We   = (const float*)d_in[15];
  const float* g2ae   = (const float*)d_in[16];
  const float* g2b    = (const float*)d_in[17];
  const float* Wes    = (const float*)d_in[18];
  const float* bes    = (const float*)d_in[19];
  const float* Wc1    = (const float*)d_in[20];
  const float* bc1    = (const float*)d_in[21];
  const float* Wc2    = (const float*)d_in[22];
  const float* bc2    = (const float*)d_in[23];
  const int*   stops  = (const int*)d_in[24];
  const int*   eidx   = (const int*)d_in[25];
  const int*   wd     = (const int*)d_in[26];
  const int*   vh     = (const int*)d_in[27];
  const int*   cp     = (const int*)d_in[28];
  float* out = (float*)d_out;
  float* ws = (float*)d_ws;

  const int*   csrc   = (const int*)(ws+WS_CSRC);
  const float* cea    = ws+WS_CEA;
  const int*   starts = (const int*)(ws+WS_STARTS);
  const int*   deg    = (const int*)(ws+WS_DEG);
  const float* lattr  = ws+WS_LATTR;

  k_prep<<<676,256,0,stream>>>(demand, g1W, g1as, g1ad, stops, Wes, dist, markov, eidx,
                               g1We, g1ae, g2We, g2ae, g2W, g2as, g2ad, ws);
  k_scansc<<<32,512,0,stream>>>(eidx, ws);
  k_agg<1><<<512,256,0,stream>>>(ws+WS_H, ws+WS_ASRC, ws+WS_ADST, csrc, cea, starts, deg,
                                 lattr, ws+WS_AE, g1b, dist, markov, ws);
  k_agg<2><<<512,256,0,stream>>>(ws+WS_H2, ws+WS_ASRC2, ws+WS_ADST2, csrc, cea, starts, deg,
                                 lattr, ws+WS_AE+8, g2b, dist, markov, ws);
  k_skpack<<<512,1024,0,stream>>>(Wc1, bc1, bes, Wweek, Wcap, Wveh, wd, vh, cp, Wc2, ws);
  gemm_mfma<true,true><<<dim3(8,8),256,0,stream>>>((const bf16*)(ws+WS_APACK), (const bf16*)(ws+WS_BPACK),
                                                   ws+WS_K, nullptr, (bf16*)(ws+WS_OUT1), 512, 512, K1);
  gemm_mfma<false,false><<<dim3(8,8),256,0,stream>>>((const bf16*)(ws+WS_OUT1), (const bf16*)(ws+WS_WC2B),
                                                     bc2, out, nullptr, 512, 512, 512);
}